// Round 22
// baseline (148.775 us; speedup 1.0000x reference)
//
#include <hip/hip_runtime.h>
#include <hip/hip_bf16.h>

#define NRES   768
#define C_S    256
#define C_P    128
#define FEAT   64
#define NTILES (NRES * (NRES / 64))   // 9216
#define NEDGE  (NRES * NRES)          // 589824
#define NBLK   768                    // persistent blocks; NTILES/NBLK = 12

typedef float f32x4 __attribute__((ext_vector_type(4)));
typedef short s16x8 __attribute__((ext_vector_type(8)));
typedef short s16x4 __attribute__((ext_vector_type(4)));

// HW RNE conversion (R19 win).
__device__ __forceinline__ short to_bf16(float f) {
    return (short)__bfloat16_as_ushort(__float2bfloat16(f));
}

// ---------------------------------------------------------------------------
__device__ __forceinline__ int bin_idx(float d) {
    const float lo0  = 0.001f;
    const float step = (20.0f - 0.001f) / 21.0f;
    int k = (int)floorf((d - lo0) / step);
    if (k < -1) k = -1;
    if (k > 21) k = 21;
    for (int kk = k + 1; kk >= k - 1; --kk) {
        if (kk < 0 || kk > 21) continue;
        float lk = lo0 + (float)kk * step;
        float uk = (kk < 21) ? (lo0 + (float)(kk + 1) * step) : 1e8f;
        if (d > lk && d < uk) return kk;
    }
    return -1;
}

// ---------------------------------------------------------------------------
// Merged setup: node(768) | wcomb(65) | wt(256) | bins(2304) in ONE launch.
#define SB_NODE  NRES                       // 768
#define SB_WCOMB (SB_NODE + FEAT + 1)       // +65  -> 833
#define SB_WT    (SB_WCOMB + 2 * C_P)       // +256 -> 1089
#define SB_BINS  (SB_WT + NEDGE / 256)      // +2304 -> 3393

__global__ __launch_bounds__(256) void setup_kernel(
    const float* __restrict__ s, const float* __restrict__ dm,
    const float* __restrict__ W_sp, const float* __restrict__ b_sp,
    const float* __restrict__ W1, const float* __restrict__ b1,
    const float* __restrict__ W_rp, const float* __restrict__ b_rp,
    const float* __restrict__ W2, const float* __restrict__ W3,
    const float* __restrict__ tp, const float* __restrict__ sp,
    float* __restrict__ A, float* __restrict__ Bt,
    float* __restrict__ Wcomb, short* __restrict__ Wt2, short* __restrict__ Wt3,
    unsigned short* __restrict__ bins)
{
    const int b = blockIdx.x;
    const int t = threadIdx.x;

    if (b < SB_NODE) {
        __shared__ float srow[C_S];
        __shared__ float psh[FEAT];
        const int i = b;
        srow[t] = s[i * C_S + t];
        __syncthreads();
        if (t < FEAT) {
            float acc = b_sp[t];
            for (int m = 0; m < C_S; ++m) acc = fmaf(srow[m], W_sp[m * FEAT + t], acc);
            psh[t] = acc;
        }
        __syncthreads();
        if (t < C_P) {
            const float d = dm[i];
            float accA = fmaf(d, W1[236 * C_P + t], b1[t]);
            float accB = d * W1[237 * C_P + t];
            for (int k = 0; k < FEAT; ++k) {
                float p = psh[k];
                accA = fmaf(p, W1[k * C_P + t], accA);
                accB = fmaf(p, W1[(FEAT + k) * C_P + t], accB);
            }
            A[i * C_P + t]  = accA;
            Bt[i * C_P + t] = accB;
        }
    } else if (b < SB_WCOMB) {
        if (t < C_P) {
            const int k = b - SB_NODE;
            float acc = 0.0f;
            if (k < FEAT) {
                for (int m = 0; m < FEAT; ++m)
                    acc = fmaf(W_rp[k * FEAT + m], W1[(2 * FEAT + m) * C_P + t], acc);
            } else {
                for (int m = 0; m < FEAT; ++m)
                    acc = fmaf(b_rp[m], W1[(2 * FEAT + m) * C_P + t], acc);
            }
            Wcomb[k * C_P + t] = acc;
        }
    } else if (b < SB_WT) {
        if (t < C_P) {
            const int nb = b - SB_WCOMB;
            const int n = nb & 127;
            if (nb < 128) Wt2[n * C_P + t] = to_bf16(W2[t * C_P + n]);
            else          Wt3[n * C_P + t] = to_bf16(W3[t * C_P + n]);
        }
    } else {
        const int idx = (b - SB_WT) * 256 + t;
        if (idx < NEDGE) {
            const int i = idx / NRES;
            const int j = idx - i * NRES;
            float dx = tp[i*3+0] - tp[j*3+0];
            float dy = tp[i*3+1] - tp[j*3+1];
            float dz = tp[i*3+2] - tp[j*3+2];
            const int bd = bin_idx(sqrtf(dx*dx + dy*dy + dz*dz));
            dx = sp[i*3+0] - sp[j*3+0];
            dy = sp[i*3+1] - sp[j*3+1];
            dz = sp[i*3+2] - sp[j*3+2];
            const int bs = bin_idx(sqrtf(dx*dx + dy*dy + dz*dz));
            bins[idx] = (unsigned short)((bd + 1) | ((bs + 1) << 8));
        }
    }
}

// ---------------------------------------------------------------------------
__global__ void rp_kernel(const float* __restrict__ Wcomb, float* __restrict__ RP) {
    __shared__ float emb[FEAT];
    const int bi = blockIdx.x;            // 0..1534
    const float d = (float)(bi - (NRES - 1));
    const int c = threadIdx.x;            // 128
    if (c < FEAT / 2) {
        float expo = 2.0f * (float)c / (float)FEAT;
        float freq = 3.14159265358979323846f / powf(2056.0f, expo);
        float ang = d * freq;
        emb[c]            = sinf(ang);
        emb[c + FEAT / 2] = cosf(ang);
    }
    __syncthreads();
    float acc = Wcomb[FEAT * C_P + c];
    for (int k = 0; k < FEAT; ++k) acc = fmaf(emb[k], Wcomb[k * C_P + c], acc);
    RP[bi * C_P + c] = acc;
}

// ---------------------------------------------------------------------------
// R22 slim phase-1 staging (deconfounds R15): loop-top issue carries only
// aCh+B+RP+bins (~40 regs, was ~72). Wd/Ws rows issued MID-iteration
// (between layer-2 and B2) — the h2 bounce + barrier + layer-3 (~300+ cyc)
// cover their latency before commit. Weights stay HOISTED (R15's real
// regression). Target: ~165-reg footprint -> 3 waves/SIMD (was 2).
__device__ __forceinline__ void p1_issue(
    int i, int j0, int c4, int er,
    const float* __restrict__ A, const float* __restrict__ Bt,
    const float* __restrict__ RP, const unsigned short* __restrict__ bins,
    f32x4& aCh, f32x4* bv, f32x4* rv, unsigned* pk)
{
    aCh = *(const f32x4*)(A + i * C_P + c4 * 4);
#pragma unroll
    for (int it = 0; it < 4; ++it) {
        const int e = it * 16 + er;
        const int j = j0 + e;
        bv[it] = *(const f32x4*)(Bt + j * C_P + c4 * 4);
        rv[it] = *(const f32x4*)(RP + (i - j + NRES - 1) * C_P + c4 * 4);
        pk[it] = bins[i * NRES + j];
    }
}

__device__ __forceinline__ void pw_issue(
    int c4, const float* __restrict__ W1, const unsigned* pk,
    f32x4* wdv, f32x4* wsv)
{
#pragma unroll
    for (int it = 0; it < 4; ++it) {
        const int bd = (int)(pk[it] & 0xffu) - 1;
        const int bs = (int)(pk[it] >> 8) - 1;
        wdv[it] = *(const f32x4*)(W1 + (192 + (bd < 0 ? 0 : bd)) * C_P + c4 * 4);
        wsv[it] = *(const f32x4*)(W1 + (214 + (bs < 0 ? 0 : bs)) * C_P + c4 * 4);
    }
}

__device__ __forceinline__ void p1_commit(
    short* buf, int c4, int er,
    const f32x4& aCh, const f32x4* bv, const f32x4* rv,
    const f32x4* wdv, const f32x4* wsv, const unsigned* pk)
{
#pragma unroll
    for (int it = 0; it < 4; ++it) {
        const int e = it * 16 + er;
        const float fd = ((pk[it] & 0xffu) == 0u) ? 0.0f : 1.0f;
        const float fs = ((pk[it] >> 8) == 0u) ? 0.0f : 1.0f;
        s16x4 pkv;
#pragma unroll
        for (int u = 0; u < 4; ++u)
            pkv[u] = to_bf16(fmaxf(
                aCh[u] + bv[it][u] + rv[it][u] + fd * wdv[it][u] + fs * wsv[it][u],
                0.0f));
        const int byt = (e * 256 + c4 * 8) ^ ((e & 15) << 4);
        *(s16x4*)((char*)buf + byt) = pkv;
    }
}

// ---------------------------------------------------------------------------
// Edge kernel = R19 VERBATIM except slim prefetch + mid-iteration Wd/Ws issue.
// Ledger: R15 +80 (confounded), R16 +12, R17 +21, R18 -10, R19 -2.5,
// R20 ±0, R21 ±0 (drain exonerated; fences were R17's cost).
__global__ __launch_bounds__(512, 1) void edge_kernel(
    const float* __restrict__ A, const float* __restrict__ Bt,
    const float* __restrict__ RP, const float* __restrict__ W1,
    const short* __restrict__ Wt2, const short* __restrict__ Wt3,
    const float* __restrict__ b2, const float* __restrict__ b3,
    const float* __restrict__ lng, const float* __restrict__ lnb,
    const unsigned short* __restrict__ bins,
    const float* __restrict__ pm, float* __restrict__ out)
{
    __shared__ short h1a[64 * C_P];
    __shared__ short h1b[64 * C_P];
    __shared__ short h2s[64 * C_P];
    __shared__ float redS[64 * 4];
    __shared__ float redQ[64 * 4];

    const int t    = threadIdx.x;
    const int lane = t & 63;
    const int q    = t >> 6;       // wave 0..7
    const int m    = lane & 15;
    const int kg   = lane >> 4;
    const int wq   = q >> 2;       // edge half
    const int cq   = q & 3;        // channel quarter
    const int c0   = cq * 32;
    const int c4   = t & 31;       // phase-1 chunk
    const int er   = t >> 5;       // phase-1 row 0..15

    // ---- hoisted (loop-invariant) weights & scale vectors ----
    s16x8 wf2[2][4], wf3[2][4];
#pragma unroll
    for (int nt = 0; nt < 2; ++nt) {
        const int n = c0 + nt * 16 + m;
#pragma unroll
        for (int ks = 0; ks < 4; ++ks) {
            wf2[nt][ks] = *(const s16x8*)(Wt2 + n * C_P + ks * 32 + kg * 8);
            wf3[nt][ks] = *(const s16x8*)(Wt3 + n * C_P + ks * 32 + kg * 8);
        }
    }
    const f32x4 b2f0 = *(const f32x4*)(b2 + c0 + kg * 4);
    const f32x4 b2f1 = *(const f32x4*)(b2 + c0 + 16 + kg * 4);
    const f32x4 b3f0 = *(const f32x4*)(b3 + c0 + kg * 4);
    const f32x4 b3f1 = *(const f32x4*)(b3 + c0 + 16 + kg * 4);
    const f32x4 gf0  = *(const f32x4*)(lng + c0 + kg * 4);
    const f32x4 gf1  = *(const f32x4*)(lng + c0 + 16 + kg * 4);
    const f32x4 bbf0 = *(const f32x4*)(lnb + c0 + kg * 4);
    const f32x4 bbf1 = *(const f32x4*)(lnb + c0 + 16 + kg * 4);

    short* cur = h1a;
    short* nxt = h1b;

    // ---- prologue: phase-1 of first tile -> cur ----
    {
        const int tile = blockIdx.x;
        const int i = tile / 12, j0 = (tile % 12) * 64;
        f32x4 aCh, bv[4], rv[4], wdv[4], wsv[4];
        unsigned pk[4];
        p1_issue(i, j0, c4, er, A, Bt, RP, bins, aCh, bv, rv, pk);
        pw_issue(c4, W1, pk, wdv, wsv);
        p1_commit(cur, c4, er, aCh, bv, rv, wdv, wsv, pk);
    }
    __syncthreads();

    for (int k = 0; k < 12; ++k) {
        const int tile = blockIdx.x + k * NBLK;
        const int i = tile / 12, j0 = (tile % 12) * 64;

        float pmv[2];
#pragma unroll
        for (int et = 0; et < 2; ++et)
            pmv[et] = pm[i * NRES + j0 + wq * 32 + et * 16 + m];

        // ---- issue next tile's slim prefetch (hides under MFMA) ----
        f32x4 aN, bN[4], rN[4];
        unsigned pkN[4];
        const bool hasNext = (k < 11);
        if (hasNext) {
            const int ntile = tile + NBLK;
            p1_issue(ntile / 12, (ntile % 12) * 64, c4, er, A, Bt, RP, bins,
                     aN, bN, rN, pkN);
        }

        // ---------- layer 2: MFMA on cur ----------
        f32x4 acc[2][2];
#pragma unroll
        for (int et = 0; et < 2; ++et) { acc[0][et] = b2f0; acc[1][et] = b2f1; }
#pragma unroll
        for (int ks = 0; ks < 4; ++ks) {
#pragma unroll
            for (int et = 0; et < 2; ++et) {
                const int e = wq * 32 + et * 16 + m;
                const int byt = (e * 256 + (ks * 32 + kg * 8) * 2) ^ (m << 4);
                s16x8 hf = *(const s16x8*)((const char*)cur + byt);
                acc[0][et] = __builtin_amdgcn_mfma_f32_16x16x32_bf16(wf2[0][ks], hf, acc[0][et], 0, 0, 0);
                acc[1][et] = __builtin_amdgcn_mfma_f32_16x16x32_bf16(wf2[1][ks], hf, acc[1][et], 0, 0, 0);
            }
        }

        // ---- issue next tile's Wd/Ws rows (bins already in regs; latency
        //      covered by h2 bounce + B2 + layer 3 before commit) ----
        f32x4 wdN[4], wsN[4];
        if (hasNext) pw_issue(c4, W1, pkN, wdN, wsN);

        // ---------- h2 bounce ----------
#pragma unroll
        for (int nt = 0; nt < 2; ++nt) {
            const int nb = (c0 + nt * 16 + kg * 4) * 2;
#pragma unroll
            for (int et = 0; et < 2; ++et) {
                const int e = wq * 32 + et * 16 + m;
                s16x4 pkv;
#pragma unroll
                for (int r = 0; r < 4; ++r) pkv[r] = to_bf16(fmaxf(acc[nt][et][r], 0.0f));
                const int byt = (e * 256 + nb) ^ (m << 4);
                *(s16x4*)((char*)h2s + byt) = pkv;
            }
        }
        __syncthreads();   // B2: h2 ready

        // ---------- layer 3 ----------
        f32x4 acc3[2][2];
#pragma unroll
        for (int et = 0; et < 2; ++et) { acc3[0][et] = b3f0; acc3[1][et] = b3f1; }
#pragma unroll
        for (int ks = 0; ks < 4; ++ks) {
#pragma unroll
            for (int et = 0; et < 2; ++et) {
                const int e = wq * 32 + et * 16 + m;
                const int byt = (e * 256 + (ks * 32 + kg * 8) * 2) ^ (m << 4);
                s16x8 hf = *(const s16x8*)((const char*)h2s + byt);
                acc3[0][et] = __builtin_amdgcn_mfma_f32_16x16x32_bf16(wf3[0][ks], hf, acc3[0][et], 0, 0, 0);
                acc3[1][et] = __builtin_amdgcn_mfma_f32_16x16x32_bf16(wf3[1][ks], hf, acc3[1][et], 0, 0, 0);
            }
        }

        // ---- commit next tile's h1 into nxt (all loads returned by now) ----
        if (hasNext)
            p1_commit(nxt, c4, er, aN, bN, rN, wdN, wsN, pkN);

        // ---------- LN stats ----------
        float pS[2], pQ[2];
#pragma unroll
        for (int et = 0; et < 2; ++et) {
            float s0 = 0.0f, s1 = 0.0f;
#pragma unroll
            for (int nt = 0; nt < 2; ++nt)
#pragma unroll
                for (int r = 0; r < 4; ++r) {
                    float x = acc3[nt][et][r];
                    s0 += x;
                    s1 = fmaf(x, x, s1);
                }
            s0 += __shfl_xor(s0, 16);
            s0 += __shfl_xor(s0, 32);
            s1 += __shfl_xor(s1, 16);
            s1 += __shfl_xor(s1, 32);
            pS[et] = s0;
            pQ[et] = s1;
        }
        if (kg < 2) {
            const float vS = (kg == 0) ? pS[0] : pS[1];
            const float vQ = (kg == 0) ? pQ[0] : pQ[1];
            redS[(wq * 32 + kg * 16 + m) * 4 + cq] = vS;
            redQ[(wq * 32 + kg * 16 + m) * 4 + cq] = vQ;
        }
        __syncthreads();   // B3: stats ready (also orders nxt writes)

        // ---------- epilogue ----------
#pragma unroll
        for (int et = 0; et < 2; ++et) {
            const int e = wq * 32 + et * 16 + m;
            f32x4 vS = *(const f32x4*)&redS[e * 4];
            f32x4 vQ = *(const f32x4*)&redQ[e * 4];
            const float mu  = (vS[0] + vS[1] + vS[2] + vS[3]) * (1.0f / 128.0f);
            const float ex2 = (vQ[0] + vQ[1] + vQ[2] + vQ[3]) * (1.0f / 128.0f);
            const float inv = rsqrtf(ex2 - mu * mu + 1e-5f);
            f32x4 o;
#pragma unroll
            for (int r = 0; r < 4; ++r)
                o[r] = ((acc3[0][et][r] - mu) * inv * gf0[r] + bbf0[r]) * pmv[et];
            *(f32x4*)(out + ((size_t)(i * NRES + j0 + e)) * C_P + c0 + kg * 4) = o;
#pragma unroll
            for (int r = 0; r < 4; ++r)
                o[r] = ((acc3[1][et][r] - mu) * inv * gf1[r] + bbf1[r]) * pmv[et];
            *(f32x4*)(out + ((size_t)(i * NRES + j0 + e)) * C_P + c0 + 16 + kg * 4) = o;
        }

        short* tmp = cur; cur = nxt; nxt = tmp;
    }
}

// ---------------------------------------------------------------------------
extern "C" void kernel_launch(void* const* d_in, const int* in_sizes, int n_in,
                              void* d_out, int out_size, void* d_ws, size_t ws_size,
                              hipStream_t stream) {
    const float* s    = (const float*)d_in[0];
    const float* tpos = (const float*)d_in[1];
    const float* scp  = (const float*)d_in[2];
    const float* pm   = (const float*)d_in[3];
    const float* dm   = (const float*)d_in[4];
    const float* W_sp = (const float*)d_in[5];
    const float* b_sp = (const float*)d_in[6];
    const float* W_rp = (const float*)d_in[7];
    const float* b_rp = (const float*)d_in[8];
    const float* W1   = (const float*)d_in[9];
    const float* b1   = (const float*)d_in[10];
    const float* W2   = (const float*)d_in[11];
    const float* b2   = (const float*)d_in[12];
    const float* W3   = (const float*)d_in[13];
    const float* b3   = (const float*)d_in[14];
    const float* lng  = (const float*)d_in[15];
    const float* lnb  = (const float*)d_in[16];
    float* out = (float*)d_out;

    float* ws    = (float*)d_ws;
    float* A     = ws;                        // 768*128 f32
    float* Bt    = A + NRES * C_P;            // 768*128 f32
    float* Wcomb = Bt + NRES * C_P;           // 65*128 f32
    float* RP    = Wcomb + (FEAT + 1) * C_P;  // 1535*128 f32
    short* Wt2   = (short*)(RP + (2 * NRES - 1) * C_P);  // 128*128 bf16
    short* Wt3   = Wt2 + C_P * C_P;
    unsigned short* bins = (unsigned short*)(Wt3 + C_P * C_P); // 768*768

    setup_kernel<<<SB_BINS, 256, 0, stream>>>(
        s, dm, W_sp, b_sp, W1, b1, W_rp, b_rp, W2, W3, tpos, scp,
        A, Bt, Wcomb, Wt2, Wt3, bins);
    rp_kernel<<<2 * NRES - 1, 128, 0, stream>>>(Wcomb, RP);
    edge_kernel<<<NBLK, 512, 0, stream>>>(A, Bt, RP, W1, Wt2, Wt3, b2, b3,
                                          lng, lnb, bins, pm, out);
}

// Round 23
// 147.207 us; speedup vs baseline: 1.0107x; 1.0107x over previous
//
#include <hip/hip_runtime.h>
#include <hip/hip_bf16.h>

#define NRES   768
#define C_S    256
#define C_P    128
#define FEAT   64
#define NTILES (NRES * (NRES / 64))   // 9216
#define NEDGE  (NRES * NRES)          // 589824
#define NBLK   768                    // persistent blocks; NTILES/NBLK = 12

typedef float f32x4 __attribute__((ext_vector_type(4)));
typedef short s16x8 __attribute__((ext_vector_type(8)));
typedef short s16x4 __attribute__((ext_vector_type(4)));

// HW RNE conversion (R19 win: compiler emits v_cvt path; same rounding).
__device__ __forceinline__ short to_bf16(float f) {
    return (short)__bfloat16_as_ushort(__float2bfloat16(f));
}

// ---------------------------------------------------------------------------
__device__ __forceinline__ int bin_idx(float d) {
    const float lo0  = 0.001f;
    const float step = (20.0f - 0.001f) / 21.0f;
    int k = (int)floorf((d - lo0) / step);
    if (k < -1) k = -1;
    if (k > 21) k = 21;
    for (int kk = k + 1; kk >= k - 1; --kk) {
        if (kk < 0 || kk > 21) continue;
        float lk = lo0 + (float)kk * step;
        float uk = (kk < 21) ? (lo0 + (float)(kk + 1) * step) : 1e8f;
        if (d > lk && d < uk) return kk;
    }
    return -1;
}

// ---------------------------------------------------------------------------
// Merged setup: node(768) | wcomb(65) | wt(256) | bins(2304) in ONE launch.
#define SB_NODE  NRES                       // 768
#define SB_WCOMB (SB_NODE + FEAT + 1)       // +65  -> 833
#define SB_WT    (SB_WCOMB + 2 * C_P)       // +256 -> 1089
#define SB_BINS  (SB_WT + NEDGE / 256)      // +2304 -> 3393

__global__ __launch_bounds__(256) void setup_kernel(
    const float* __restrict__ s, const float* __restrict__ dm,
    const float* __restrict__ W_sp, const float* __restrict__ b_sp,
    const float* __restrict__ W1, const float* __restrict__ b1,
    const float* __restrict__ W_rp, const float* __restrict__ b_rp,
    const float* __restrict__ W2, const float* __restrict__ W3,
    const float* __restrict__ tp, const float* __restrict__ sp,
    float* __restrict__ A, float* __restrict__ Bt,
    float* __restrict__ Wcomb, short* __restrict__ Wt2, short* __restrict__ Wt3,
    unsigned short* __restrict__ bins)
{
    const int b = blockIdx.x;
    const int t = threadIdx.x;

    if (b < SB_NODE) {
        __shared__ float srow[C_S];
        __shared__ float psh[FEAT];
        const int i = b;
        srow[t] = s[i * C_S + t];
        __syncthreads();
        if (t < FEAT) {
            float acc = b_sp[t];
            for (int m = 0; m < C_S; ++m) acc = fmaf(srow[m], W_sp[m * FEAT + t], acc);
            psh[t] = acc;
        }
        __syncthreads();
        if (t < C_P) {
            const float d = dm[i];
            float accA = fmaf(d, W1[236 * C_P + t], b1[t]);
            float accB = d * W1[237 * C_P + t];
            for (int k = 0; k < FEAT; ++k) {
                float p = psh[k];
                accA = fmaf(p, W1[k * C_P + t], accA);
                accB = fmaf(p, W1[(FEAT + k) * C_P + t], accB);
            }
            A[i * C_P + t]  = accA;
            Bt[i * C_P + t] = accB;
        }
    } else if (b < SB_WCOMB) {
        if (t < C_P) {
            const int k = b - SB_NODE;
            float acc = 0.0f;
            if (k < FEAT) {
                for (int m = 0; m < FEAT; ++m)
                    acc = fmaf(W_rp[k * FEAT + m], W1[(2 * FEAT + m) * C_P + t], acc);
            } else {
                for (int m = 0; m < FEAT; ++m)
                    acc = fmaf(b_rp[m], W1[(2 * FEAT + m) * C_P + t], acc);
            }
            Wcomb[k * C_P + t] = acc;
        }
    } else if (b < SB_WT) {
        if (t < C_P) {
            const int nb = b - SB_WCOMB;
            const int n = nb & 127;
            if (nb < 128) Wt2[n * C_P + t] = to_bf16(W2[t * C_P + n]);
            else          Wt3[n * C_P + t] = to_bf16(W3[t * C_P + n]);
        }
    } else {
        const int idx = (b - SB_WT) * 256 + t;
        if (idx < NEDGE) {
            const int i = idx / NRES;
            const int j = idx - i * NRES;
            float dx = tp[i*3+0] - tp[j*3+0];
            float dy = tp[i*3+1] - tp[j*3+1];
            float dz = tp[i*3+2] - tp[j*3+2];
            const int bd = bin_idx(sqrtf(dx*dx + dy*dy + dz*dz));
            dx = sp[i*3+0] - sp[j*3+0];
            dy = sp[i*3+1] - sp[j*3+1];
            dz = sp[i*3+2] - sp[j*3+2];
            const int bs = bin_idx(sqrtf(dx*dx + dy*dy + dz*dz));
            bins[idx] = (unsigned short)((bd + 1) | ((bs + 1) << 8));
        }
    }
}

// ---------------------------------------------------------------------------
__global__ void rp_kernel(const float* __restrict__ Wcomb, float* __restrict__ RP) {
    __shared__ float emb[FEAT];
    const int bi = blockIdx.x;            // 0..1534
    const float d = (float)(bi - (NRES - 1));
    const int c = threadIdx.x;            // 128
    if (c < FEAT / 2) {
        float expo = 2.0f * (float)c / (float)FEAT;
        float freq = 3.14159265358979323846f / powf(2056.0f, expo);
        float ang = d * freq;
        emb[c]            = sinf(ang);
        emb[c + FEAT / 2] = cosf(ang);
    }
    __syncthreads();
    float acc = Wcomb[FEAT * C_P + c];
    for (int k = 0; k < FEAT; ++k) acc = fmaf(emb[k], Wcomb[k * C_P + c], acc);
    RP[bi * C_P + c] = acc;
}

// ---------------------------------------------------------------------------
// Phase-1 staging helpers (issue loads early; commit writes late — T14).
__device__ __forceinline__ void p1_issue(
    int i, int j0, int c4, int er,
    const float* __restrict__ A, const float* __restrict__ Bt,
    const float* __restrict__ RP, const float* __restrict__ W1,
    const unsigned short* __restrict__ bins,
    f32x4& aCh, f32x4* bv, f32x4* rv, f32x4* wdv, f32x4* wsv,
    float* fd, float* fs)
{
    aCh = *(const f32x4*)(A + i * C_P + c4 * 4);
#pragma unroll
    for (int it = 0; it < 4; ++it) {
        const int e = it * 16 + er;
        const int j = j0 + e;
        bv[it] = *(const f32x4*)(Bt + j * C_P + c4 * 4);
        rv[it] = *(const f32x4*)(RP + (i - j + NRES - 1) * C_P + c4 * 4);
        const unsigned pk = bins[i * NRES + j];
        const int bd = (int)(pk & 0xffu) - 1;
        const int bs = (int)(pk >> 8) - 1;
        wdv[it] = *(const f32x4*)(W1 + (192 + (bd < 0 ? 0 : bd)) * C_P + c4 * 4);
        wsv[it] = *(const f32x4*)(W1 + (214 + (bs < 0 ? 0 : bs)) * C_P + c4 * 4);
        fd[it] = (bd < 0) ? 0.0f : 1.0f;
        fs[it] = (bs < 0) ? 0.0f : 1.0f;
    }
}

__device__ __forceinline__ void p1_commit(
    short* buf, int c4, int er,
    const f32x4& aCh, const f32x4* bv, const f32x4* rv,
    const f32x4* wdv, const f32x4* wsv, const float* fd, const float* fs)
{
#pragma unroll
    for (int it = 0; it < 4; ++it) {
        const int e = it * 16 + er;
        s16x4 pkv;
#pragma unroll
        for (int u = 0; u < 4; ++u)
            pkv[u] = to_bf16(fmaxf(
                aCh[u] + bv[it][u] + rv[it][u] + fd[it] * wdv[it][u] + fs[it] * wsv[it][u],
                0.0f));
        const int byt = (e * 256 + c4 * 8) ^ ((e & 15) << 4);
        *(s16x4*)((char*)buf + byt) = pkv;
    }
}

// ---------------------------------------------------------------------------
// Edge kernel = R19 VERBATIM (best measured: 147.4us). Final configuration:
// cross-tile pipeline (issue-early/commit-late), hoisted weights, full
// 17-load prefetch, 2 plain __syncthreads/tile, strided tile map, HW cvt.
// Neighborhood ledger (all single-variable): R15 JIT-weights +80; R16
// row-local map +12; R17 fenced lds-barrier +21; R20 half-blocks ±0;
// R21 drain-free barrier ±0; R22 slim prefetch ±0. Session: 650 -> 147us.
__global__ __launch_bounds__(512, 1) void edge_kernel(
    const float* __restrict__ A, const float* __restrict__ Bt,
    const float* __restrict__ RP, const float* __restrict__ W1,
    const short* __restrict__ Wt2, const short* __restrict__ Wt3,
    const float* __restrict__ b2, const float* __restrict__ b3,
    const float* __restrict__ lng, const float* __restrict__ lnb,
    const unsigned short* __restrict__ bins,
    const float* __restrict__ pm, float* __restrict__ out)
{
    __shared__ short h1a[64 * C_P];
    __shared__ short h1b[64 * C_P];
    __shared__ short h2s[64 * C_P];
    __shared__ float redS[64 * 4];
    __shared__ float redQ[64 * 4];

    const int t    = threadIdx.x;
    const int lane = t & 63;
    const int q    = t >> 6;       // wave 0..7
    const int m    = lane & 15;
    const int kg   = lane >> 4;
    const int wq   = q >> 2;       // edge half
    const int cq   = q & 3;        // channel quarter
    const int c0   = cq * 32;
    const int c4   = t & 31;       // phase-1 chunk
    const int er   = t >> 5;       // phase-1 row 0..15

    // ---- hoisted (loop-invariant) weights & scale vectors ----
    s16x8 wf2[2][4], wf3[2][4];
#pragma unroll
    for (int nt = 0; nt < 2; ++nt) {
        const int n = c0 + nt * 16 + m;
#pragma unroll
        for (int ks = 0; ks < 4; ++ks) {
            wf2[nt][ks] = *(const s16x8*)(Wt2 + n * C_P + ks * 32 + kg * 8);
            wf3[nt][ks] = *(const s16x8*)(Wt3 + n * C_P + ks * 32 + kg * 8);
        }
    }
    const f32x4 b2f0 = *(const f32x4*)(b2 + c0 + kg * 4);
    const f32x4 b2f1 = *(const f32x4*)(b2 + c0 + 16 + kg * 4);
    const f32x4 b3f0 = *(const f32x4*)(b3 + c0 + kg * 4);
    const f32x4 b3f1 = *(const f32x4*)(b3 + c0 + 16 + kg * 4);
    const f32x4 gf0  = *(const f32x4*)(lng + c0 + kg * 4);
    const f32x4 gf1  = *(const f32x4*)(lng + c0 + 16 + kg * 4);
    const f32x4 bbf0 = *(const f32x4*)(lnb + c0 + kg * 4);
    const f32x4 bbf1 = *(const f32x4*)(lnb + c0 + 16 + kg * 4);

    short* cur = h1a;
    short* nxt = h1b;

    // ---- prologue: phase-1 of first tile -> cur ----
    {
        const int tile = blockIdx.x;
        const int i = tile / 12, j0 = (tile % 12) * 64;
        f32x4 aCh, bv[4], rv[4], wdv[4], wsv[4];
        float fd[4], fs[4];
        p1_issue(i, j0, c4, er, A, Bt, RP, W1, bins, aCh, bv, rv, wdv, wsv, fd, fs);
        p1_commit(cur, c4, er, aCh, bv, rv, wdv, wsv, fd, fs);
    }
    __syncthreads();

    for (int k = 0; k < 12; ++k) {
        const int tile = blockIdx.x + k * NBLK;
        const int i = tile / 12, j0 = (tile % 12) * 64;

        float pmv[2];
#pragma unroll
        for (int et = 0; et < 2; ++et)
            pmv[et] = pm[i * NRES + j0 + wq * 32 + et * 16 + m];

        // ---- issue next tile's phase-1 loads (latency hides under MFMA) ----
        f32x4 aN, bN[4], rN[4], wdN[4], wsN[4];
        float fdN[4], fsN[4];
        const bool hasNext = (k < 11);
        if (hasNext) {
            const int ntile = tile + NBLK;
            p1_issue(ntile / 12, (ntile % 12) * 64, c4, er, A, Bt, RP, W1, bins,
                     aN, bN, rN, wdN, wsN, fdN, fsN);
        }

        // ---------- layer 2: MFMA on cur ----------
        f32x4 acc[2][2];
#pragma unroll
        for (int et = 0; et < 2; ++et) { acc[0][et] = b2f0; acc[1][et] = b2f1; }
#pragma unroll
        for (int ks = 0; ks < 4; ++ks) {
#pragma unroll
            for (int et = 0; et < 2; ++et) {
                const int e = wq * 32 + et * 16 + m;
                const int byt = (e * 256 + (ks * 32 + kg * 8) * 2) ^ (m << 4);
                s16x8 hf = *(const s16x8*)((const char*)cur + byt);
                acc[0][et] = __builtin_amdgcn_mfma_f32_16x16x32_bf16(wf2[0][ks], hf, acc[0][et], 0, 0, 0);
                acc[1][et] = __builtin_amdgcn_mfma_f32_16x16x32_bf16(wf2[1][ks], hf, acc[1][et], 0, 0, 0);
            }
        }

        // ---------- h2 bounce ----------
#pragma unroll
        for (int nt = 0; nt < 2; ++nt) {
            const int nb = (c0 + nt * 16 + kg * 4) * 2;
#pragma unroll
            for (int et = 0; et < 2; ++et) {
                const int e = wq * 32 + et * 16 + m;
                s16x4 pkv;
#pragma unroll
                for (int r = 0; r < 4; ++r) pkv[r] = to_bf16(fmaxf(acc[nt][et][r], 0.0f));
                const int byt = (e * 256 + nb) ^ (m << 4);
                *(s16x4*)((char*)h2s + byt) = pkv;
            }
        }
        __syncthreads();   // B2: h2 ready

        // ---------- layer 3 ----------
        f32x4 acc3[2][2];
#pragma unroll
        for (int et = 0; et < 2; ++et) { acc3[0][et] = b3f0; acc3[1][et] = b3f1; }
#pragma unroll
        for (int ks = 0; ks < 4; ++ks) {
#pragma unroll
            for (int et = 0; et < 2; ++et) {
                const int e = wq * 32 + et * 16 + m;
                const int byt = (e * 256 + (ks * 32 + kg * 8) * 2) ^ (m << 4);
                s16x8 hf = *(const s16x8*)((const char*)h2s + byt);
                acc3[0][et] = __builtin_amdgcn_mfma_f32_16x16x32_bf16(wf3[0][ks], hf, acc3[0][et], 0, 0, 0);
                acc3[1][et] = __builtin_amdgcn_mfma_f32_16x16x32_bf16(wf3[1][ks], hf, acc3[1][et], 0, 0, 0);
            }
        }

        // ---- commit next tile's h1 into nxt (loads returned by now) ----
        if (hasNext)
            p1_commit(nxt, c4, er, aN, bN, rN, wdN, wsN, fdN, fsN);

        // ---------- LN stats ----------
        float pS[2], pQ[2];
#pragma unroll
        for (int et = 0; et < 2; ++et) {
            float s0 = 0.0f, s1 = 0.0f;
#pragma unroll
            for (int nt = 0; nt < 2; ++nt)
#pragma unroll
                for (int r = 0; r < 4; ++r) {
                    float x = acc3[nt][et][r];
                    s0 += x;
                    s1 = fmaf(x, x, s1);
                }
            s0 += __shfl_xor(s0, 16);
            s0 += __shfl_xor(s0, 32);
            s1 += __shfl_xor(s1, 16);
            s1 += __shfl_xor(s1, 32);
            pS[et] = s0;
            pQ[et] = s1;
        }
        if (kg < 2) {
            const float vS = (kg == 0) ? pS[0] : pS[1];
            const float vQ = (kg == 0) ? pQ[0] : pQ[1];
            redS[(wq * 32 + kg * 16 + m) * 4 + cq] = vS;
            redQ[(wq * 32 + kg * 16 + m) * 4 + cq] = vQ;
        }
        __syncthreads();   // B3: stats ready (also orders nxt writes)

        // ---------- epilogue ----------
#pragma unroll
        for (int et = 0; et < 2; ++et) {
            const int e = wq * 32 + et * 16 + m;
            f32x4 vS = *(const f32x4*)&redS[e * 4];
            f32x4 vQ = *(const f32x4*)&redQ[e * 4];
            const float mu  = (vS[0] + vS[1] + vS[2] + vS[3]) * (1.0f / 128.0f);
            const float ex2 = (vQ[0] + vQ[1] + vQ[2] + vQ[3]) * (1.0f / 128.0f);
            const float inv = rsqrtf(ex2 - mu * mu + 1e-5f);
            f32x4 o;
#pragma unroll
            for (int r = 0; r < 4; ++r)
                o[r] = ((acc3[0][et][r] - mu) * inv * gf0[r] + bbf0[r]) * pmv[et];
            *(f32x4*)(out + ((size_t)(i * NRES + j0 + e)) * C_P + c0 + kg * 4) = o;
#pragma unroll
            for (int r = 0; r < 4; ++r)
                o[r] = ((acc3[1][et][r] - mu) * inv * gf1[r] + bbf1[r]) * pmv[et];
            *(f32x4*)(out + ((size_t)(i * NRES + j0 + e)) * C_P + c0 + 16 + kg * 4) = o;
        }

        short* tmp = cur; cur = nxt; nxt = tmp;
    }
}

// ---------------------------------------------------------------------------
extern "C" void kernel_launch(void* const* d_in, const int* in_sizes, int n_in,
                              void* d_out, int out_size, void* d_ws, size_t ws_size,
                              hipStream_t stream) {
    const float* s    = (const float*)d_in[0];
    const float* tpos = (const float*)d_in[1];
    const float* scp  = (const float*)d_in[2];
    const float* pm   = (const float*)d_in[3];
    const float* dm   = (const float*)d_in[4];
    const float* W_sp = (const float*)d_in[5];
    const float* b_sp = (const float*)d_in[6];
    const float* W_rp = (const float*)d_in[7];
    const float* b_rp = (const float*)d_in[8];
    const float* W1   = (const float*)d_in[9];
    const float* b1   = (const float*)d_in[10];
    const float* W2   = (const float*)d_in[11];
    const float* b2   = (const float*)d_in[12];
    const float* W3   = (const float*)d_in[13];
    const float* b3   = (const float*)d_in[14];
    const float* lng  = (const float*)d_in[15];
    const float* lnb  = (const float*)d_in[16];
    float* out = (float*)d_out;

    float* ws    = (float*)d_ws;
    float* A     = ws;                        // 768*128 f32
    float* Bt    = A + NRES * C_P;            // 768*128 f32
    float* Wcomb = Bt + NRES * C_P;           // 65*128 f32
    float* RP    = Wcomb + (FEAT + 1) * C_P;  // 1535*128 f32
    short* Wt2   = (short*)(RP + (2 * NRES - 1) * C_P);  // 128*128 bf16
    short* Wt3   = Wt2 + C_P * C_P;
    unsigned short* bins = (unsigned short*)(Wt3 + C_P * C_P); // 768*768

    setup_kernel<<<SB_BINS, 256, 0, stream>>>(
        s, dm, W_sp, b_sp, W1, b1, W_rp, b_rp, W2, W3, tpos, scp,
        A, Bt, Wcomb, Wt2, Wt3, bins);
    rp_kernel<<<2 * NRES - 1, 128, 0, stream>>>(Wcomb, RP);
    edge_kernel<<<NBLK, 512, 0, stream>>>(A, Bt, RP, W1, Wt2, Wt3, b2, b3,
                                          lng, lnb, bins, pm, out);
}